// Round 2
// baseline (175.015 us; speedup 1.0000x reference)
//
#include <hip/hip_runtime.h>
#include <hip/hip_bf16.h>
#include <math.h>

// Problem constants (reference: B,S,H,L = 16,128,512,43)
#define BB 16
#define SS 128
#define HH 512
#define LL 43
#define NEGV -10000.0f
#define M_TOT (BB*SS)   // 2048

#define LOG2E 1.44269504088896f
#define TWO_LOG2E 2.88539008177793f
#define LN2 0.69314718055995f

__device__ __forceinline__ float fast_exp2(float x) { return __builtin_amdgcn_exp2f(x); }
__device__ __forceinline__ float fast_rcp(float x)  { return __builtin_amdgcn_rcpf(x); }
__device__ __forceinline__ float fast_log2(float x) { return __builtin_amdgcn_logf(x); }
__device__ __forceinline__ float exp_fast(float x)  { return fast_exp2(x * LOG2E); }

// Input already prescaled by 2*log2(e):  tanh(x) == 1 - 2/(1 + 2^{x'}),  x' = 2*log2(e)*x
// Saturates correctly: x'->+inf: exp2->inf, rcp->0 -> 1;  x'->-inf: exp2->0 -> -1.
__device__ __forceinline__ float tanh_pre(float xp) {
    float e = fast_exp2(xp);
    return fmaf(-2.0f, fast_rcp(e + 1.0f), 1.0f);
}

// ------------------------------------------------------------------
// Kernel 1: fused GEMM
//   u'[m][n] = (repr[m]·u_w[:512,n] + u_b[n]) * 2log2e
//   w'[m][n] = (repr[m]·w_w[:512,n] + labels[m]·w_w[512:,n] + w_b[n]) * 2log2e
// Tiles: BM=BN=64, BK=16, 256 threads, 4x4 microtile, both outputs
// share the A tile.  Prescale folded into epilogue so the scores
// kernel needs no per-element multiply before exp2.
// ------------------------------------------------------------------
#define BM 64
#define BN 64
#define BK 16

__global__ __launch_bounds__(256)
void gemm_uw(const float* __restrict__ repr, const float* __restrict__ labels,
             const float* __restrict__ u_w, const float* __restrict__ u_b,
             const float* __restrict__ w_w, const float* __restrict__ w_b,
             float* __restrict__ u_out, float* __restrict__ w_out) {
    __shared__ float As[BK][BM];
    __shared__ float Bu[BK][BN];
    __shared__ float Bw[BK][BN];

    const int tid = threadIdx.x;
    const int bm  = blockIdx.x & 31;          // 32 row-blocks
    const int bn  = blockIdx.x >> 5;          // 8 col-blocks
    const int m0  = bm * BM;
    const int n0  = bn * BN;

    const int ty = tid >> 4;                  // 0..15 -> row group
    const int tx = tid & 15;                  // 0..15 -> col group

    // global-load mapping
    const int arow = tid >> 2;                // 0..63
    const int acol = (tid & 3) << 2;          // 0,4,8,12
    const int bkr  = tid >> 4;                // 0..15 (k row)
    const int bcol = (tid & 15) << 2;         // 0..60

    float acc_u[4][4];
    float acc_w[4][4];
#pragma unroll
    for (int i = 0; i < 4; ++i)
#pragma unroll
        for (int j = 0; j < 4; ++j) { acc_u[i][j] = 0.f; acc_w[i][j] = 0.f; }

    // ---- main K loop over repr (K = 512) ----
    for (int kt = 0; kt < HH / BK; ++kt) {
        const int k0 = kt * BK;
        float4 av = *(const float4*)&repr[(size_t)(m0 + arow) * HH + k0 + acol];
        As[acol + 0][arow] = av.x;
        As[acol + 1][arow] = av.y;
        As[acol + 2][arow] = av.z;
        As[acol + 3][arow] = av.w;
        float4 bu = *(const float4*)&u_w[(size_t)(k0 + bkr) * HH + n0 + bcol];
        float4 bw = *(const float4*)&w_w[(size_t)(k0 + bkr) * HH + n0 + bcol];
        *(float4*)&Bu[bkr][bcol] = bu;
        *(float4*)&Bw[bkr][bcol] = bw;
        __syncthreads();
#pragma unroll
        for (int k = 0; k < BK; ++k) {
            float4 a  = *(const float4*)&As[k][ty << 2];
            float4 fu = *(const float4*)&Bu[k][tx << 2];
            float4 fw = *(const float4*)&Bw[k][tx << 2];
            const float ar[4] = {a.x, a.y, a.z, a.w};
            const float ur[4] = {fu.x, fu.y, fu.z, fu.w};
            const float wr[4] = {fw.x, fw.y, fw.z, fw.w};
#pragma unroll
            for (int i = 0; i < 4; ++i)
#pragma unroll
                for (int j = 0; j < 4; ++j) {
                    acc_u[i][j] = fmaf(ar[i], ur[j], acc_u[i][j]);
                    acc_w[i][j] = fmaf(ar[i], wr[j], acc_w[i][j]);
                }
        }
        __syncthreads();
    }

    // ---- label tail (K = 43), contributes to w only ----
    for (int kt = 0; kt < (LL + BK - 1) / BK; ++kt) {
        const int k0 = kt * BK;
#pragma unroll
        for (int q = 0; q < 4; ++q) {
            int k = k0 + acol + q;
            As[acol + q][arow] = (k < LL) ? labels[(size_t)(m0 + arow) * LL + k] : 0.f;
        }
        {
            int k = k0 + bkr;
            float4 bw;
            if (k < LL) bw = *(const float4*)&w_w[(size_t)(HH + k) * HH + n0 + bcol];
            else        bw = make_float4(0.f, 0.f, 0.f, 0.f);
            *(float4*)&Bw[bkr][bcol] = bw;
        }
        __syncthreads();
#pragma unroll
        for (int k = 0; k < BK; ++k) {
            float4 a  = *(const float4*)&As[k][ty << 2];
            float4 fw = *(const float4*)&Bw[k][tx << 2];
            const float ar[4] = {a.x, a.y, a.z, a.w};
            const float wr[4] = {fw.x, fw.y, fw.z, fw.w};
#pragma unroll
            for (int i = 0; i < 4; ++i)
#pragma unroll
                for (int j = 0; j < 4; ++j)
                    acc_w[i][j] = fmaf(ar[i], wr[j], acc_w[i][j]);
        }
        __syncthreads();
    }

    // ---- epilogue: add bias, prescale by 2*log2(e), store ----
#pragma unroll
    for (int i = 0; i < 4; ++i) {
        const int r = m0 + (ty << 2) + i;
        const int c = n0 + (tx << 2);
        float4 ub = *(const float4*)&u_b[c];
        float4 wb = *(const float4*)&w_b[c];
        float4 ou, ow;
        ou.x = (acc_u[i][0] + ub.x) * TWO_LOG2E;
        ou.y = (acc_u[i][1] + ub.y) * TWO_LOG2E;
        ou.z = (acc_u[i][2] + ub.z) * TWO_LOG2E;
        ou.w = (acc_u[i][3] + ub.w) * TWO_LOG2E;
        ow.x = (acc_w[i][0] + wb.x) * TWO_LOG2E;
        ow.y = (acc_w[i][1] + wb.y) * TWO_LOG2E;
        ow.z = (acc_w[i][2] + wb.z) * TWO_LOG2E;
        ow.w = (acc_w[i][3] + wb.w) * TWO_LOG2E;
        *(float4*)&u_out[(size_t)r * HH + c] = ou;
        *(float4*)&w_out[(size_t)r * HH + c] = ow;
    }
}

// ------------------------------------------------------------------
// Kernel 2 (v2): j-as-lane scores.  One block = (b, 4 i-rows).
// 4 waves = (i-pair ig) x (j-half jh).  Lane owns j = jh*64+lane and
// loops over all 512 h, accumulating scores for 2 i-rows fully in
// registers — NO shuffle reduction, no LDS in the hot loop.
// w[i,h] and v[h] are wave-uniform -> scalar loads (SALU pipe).
// Then masks + probs written from registers; softmax/CE via small LDS.
// ------------------------------------------------------------------
__global__ __launch_bounds__(256)
void scores_v2(const float* __restrict__ u, const float* __restrict__ w,
               const float* __restrict__ v_w, const int* __restrict__ heads,
               const int* __restrict__ words,
               float* __restrict__ out,      // [0]=loss (kernel 3), [1..] probs
               float* __restrict__ ce_out) {
    // XCD-locality swizzle: assuming round-robin xcd = blockIdx % 8,
    // XCD x serves b in {2x, 2x+1}: per-XCD u+w working set = 1 MB < 4 MB L2.
    const int blk = blockIdx.x;               // 0..511
    const int r   = blk & 7;
    const int q   = blk >> 3;                 // 0..63
    const int b   = r * 2 + (q & 1);
    const int i0  = (q >> 1) * 4;             // 4 i-rows per block

    const int tid  = threadIdx.x;
    const int wv   = tid >> 6;                // 0..3
    const int lane = tid & 63;
    const int ig   = wv >> 1;                 // i-pair select
    const int jh   = wv & 1;                  // j-half select
    const int j    = jh * 64 + lane;
    const int ia   = i0 + ig * 2;             // first i-row of this wave

    const float* __restrict__ up  = &u[(size_t)(b * SS + j) * HH];
    const float* __restrict__ w0p = &w[(size_t)(b * SS + ia) * HH];
    const float* __restrict__ w1p = w0p + HH;

    float acc0 = 0.f, acc1 = 0.f;
#pragma unroll 2
    for (int h = 0; h < HH; h += 8) {
        float4 ua = *(const float4*)&up[h];
        float4 ub = *(const float4*)&up[h + 4];
        float4 va = *(const float4*)&v_w[h];      // uniform -> s_load
        float4 vb = *(const float4*)&v_w[h + 4];
        float4 w0a = *(const float4*)&w0p[h];     // uniform -> s_load
        float4 w0b = *(const float4*)&w0p[h + 4];
        float4 w1a = *(const float4*)&w1p[h];
        float4 w1b = *(const float4*)&w1p[h + 4];
#define STEP(UU, VV, W0, W1)                                  \
        acc0 = fmaf(VV, tanh_pre(UU + W0), acc0);             \
        acc1 = fmaf(VV, tanh_pre(UU + W1), acc1);
        STEP(ua.x, va.x, w0a.x, w1a.x)
        STEP(ua.y, va.y, w0a.y, w1a.y)
        STEP(ua.z, va.z, w0a.z, w1a.z)
        STEP(ua.w, va.w, w0a.w, w1a.w)
        STEP(ub.x, vb.x, w0b.x, w1b.x)
        STEP(ub.y, vb.y, w0b.y, w1b.y)
        STEP(ub.z, vb.z, w0b.z, w1b.z)
        STEP(ub.w, vb.w, w0b.w, w1b.w)
#undef STEP
    }

    // ---- masks (column mask identical for both i rows) ----
    const bool colpad = (words[b * SS + j] == 0);
    float s0 = (colpad || j == ia)     ? NEGV : acc0;
    float s1 = (colpad || j == ia + 1) ? NEGV : acc1;

    __shared__ float s_lds[4][SS];
    s_lds[ig * 2 + 0][j] = s0;
    s_lds[ig * 2 + 1][j] = s1;

    // ---- probs = exp(masked scores), rows i>=1 only ----
    // row i=ia (skip when ia==0), row i=ia+1 (always >=1)
    if (ia >= 1)
        out[1 + (size_t)(b * (SS - 1) + (ia - 1)) * SS + j] = exp_fast(s0);
    out[1 + (size_t)(b * (SS - 1) + ia) * SS + j] = exp_fast(s1);

    __syncthreads();

    // ---- softmax + CE: wave wv handles row i0+wv ----
    const int i  = i0 + wv;
    float t0 = s_lds[wv][lane];
    float t1 = s_lds[wv][lane + 64];
    float m = fmaxf(t0, t1);
#pragma unroll
    for (int off = 32; off > 0; off >>= 1) m = fmaxf(m, __shfl_xor(m, off));
    float e = exp_fast(t0 - m) + exp_fast(t1 - m);
#pragma unroll
    for (int off = 32; off > 0; off >>= 1) e += __shfl_xor(e, off);

    const int hd = heads[b * SS + i];
    const float sh = s_lds[wv][hd];           // masked score at head
    const float ce = m + fast_log2(e) * LN2 - sh;
    if (lane == 0) ce_out[b * SS + i] = (i >= 1) ? ce : 0.f;
}

// ------------------------------------------------------------------
// Kernel 3: deterministic loss reduction (f64 accumulate)
// ------------------------------------------------------------------
__global__ __launch_bounds__(256)
void loss_sum(const float* __restrict__ ce, float* __restrict__ out) {
    __shared__ double sd[256];
    const int tid = threadIdx.x;
    double s = 0.0;
    for (int k = tid; k < M_TOT; k += 256) s += (double)ce[k];
    sd[tid] = s;
    __syncthreads();
    for (int off = 128; off > 0; off >>= 1) {
        if (tid < off) sd[tid] += sd[tid + off];
        __syncthreads();
    }
    if (tid == 0) out[0] = (float)(sd[0] * (1.0 / (double)BB));
}

// ------------------------------------------------------------------
extern "C" void kernel_launch(void* const* d_in, const int* in_sizes, int n_in,
                              void* d_out, int out_size, void* d_ws, size_t ws_size,
                              hipStream_t stream) {
    const float* repr   = (const float*)d_in[0];   // [16,128,512]
    const float* labels = (const float*)d_in[1];   // [16,128,43]
    const int*   heads  = (const int*)d_in[2];     // [16,128]
    const int*   words  = (const int*)d_in[3];     // [16,128]
    // d_in[4] = sent_id (unused)
    const float* u_w    = (const float*)d_in[5];   // [555,512]
    const float* u_b    = (const float*)d_in[6];   // [512]
    const float* w_w    = (const float*)d_in[7];   // [555,512]
    const float* w_b    = (const float*)d_in[8];   // [512]
    const float* v_w    = (const float*)d_in[9];   // [512,1]

    float* out = (float*)d_out;                    // [0]=loss, rest probs [16,127,128]

    float* u_ws  = (float*)d_ws;                   // 2048*512 floats = 4 MB (prescaled)
    float* w_ws  = u_ws + (size_t)M_TOT * HH;      // 4 MB (prescaled)
    float* ce_ws = w_ws + (size_t)M_TOT * HH;      // 2048 floats

    gemm_uw<<<dim3(256), dim3(256), 0, stream>>>(repr, labels, u_w, u_b, w_w, w_b,
                                                 u_ws, w_ws);
    scores_v2<<<dim3(512), dim3(256), 0, stream>>>(
        u_ws, w_ws, v_w, heads, words, out, ce_ws);
    loss_sum<<<dim3(1), dim3(256), 0, stream>>>(ce_ws, out);
}